// Round 2
// baseline (1747.200 us; speedup 1.0000x reference)
//
#include <hip/hip_runtime.h>
#include <stdint.h>
#include <math.h>

#define H 8
#define NSEQ 8192
#define D 64
#define SCALE 0.125f

// ---------------- ws layout (ints/floats, 4B units) ----------------
// lse      : 65536 f32
// hash_q   : 65536 i32
// hash_k   : 65536 i32
// qidx100  : 8*4096
// kidx100  : 8*4096
// qidx101  : 16*2048
// kidx101  : 16*2048
// samp100  : 8*256
// samp101  : 16*256

__device__ __forceinline__ float4 f4scale(float4 a, float s){
  return make_float4(a.x*s, a.y*s, a.z*s, a.w*s);
}
__device__ __forceinline__ void f4fma(float4& a, float p, float4 b){
  a.x = fmaf(p, b.x, a.x); a.y = fmaf(p, b.y, a.y);
  a.z = fmaf(p, b.z, a.z); a.w = fmaf(p, b.w, a.w);
}

// ---------------- 1. LSH hash (Gray-coded sign bits) ----------------
__global__ __launch_bounds__(256) void hash_kernel(
    const float* __restrict__ q, const float* __restrict__ k,
    const float* __restrict__ proj, int* __restrict__ hq, int* __restrict__ hk)
{
  __shared__ float pj[448];
  for (int i = threadIdx.x; i < 448; i += blockDim.x) pj[i] = proj[i];
  __syncthreads();
  int idx = blockIdx.x * blockDim.x + threadIdx.x;
  if (idx >= 2 * H * NSEQ) return;
  int isk = idx >= H * NSEQ;
  int r = isk ? idx - H * NSEQ : idx;
  const float* src = (isk ? k : q) + (size_t)r * D;
  float dot[7] = {0,0,0,0,0,0,0};
  for (int d = 0; d < D; ++d){
    float x = src[d];
#pragma unroll
    for (int p = 0; p < 7; ++p) dot[p] = fmaf(x, pj[d*7+p], dot[p]);
  }
  int b = 0;
#pragma unroll
  for (int p = 0; p < 7; ++p) if (dot[p] > 0.0f) b |= (1 << p);
  int g = b ^ (b >> 1);           // _PERM[bin] == gray code
  (isk ? hk : hq)[r] = g;
}

// ---------------- 2. Threefry-2x32-20 sampled indices (partitionable PRNG) ----------------
__device__ __forceinline__ void tf2x32(uint32_t k0, uint32_t k1,
                                       uint32_t x0, uint32_t x1,
                                       uint32_t& o0, uint32_t& o1)
{
  uint32_t ks0 = k0, ks1 = k1, ks2 = k0 ^ k1 ^ 0x1BD11BDAu;
  x0 += ks0; x1 += ks1;
#define RND(r) { x0 += x1; x1 = (x1 << (r)) | (x1 >> (32-(r))); x1 ^= x0; }
  RND(13) RND(15) RND(26) RND(6)  x0 += ks1; x1 += ks2 + 1u;
  RND(17) RND(29) RND(16) RND(24) x0 += ks2; x1 += ks0 + 2u;
  RND(13) RND(15) RND(26) RND(6)  x0 += ks0; x1 += ks1 + 3u;
  RND(17) RND(29) RND(16) RND(24) x0 += ks1; x1 += ks2 + 4u;
  RND(13) RND(15) RND(26) RND(6)  x0 += ks2; x1 += ks0 + 5u;
#undef RND
  o0 = x0; o1 = x1;
}

__global__ __launch_bounds__(256) void sample_kernel(int* __restrict__ s100, int* __restrict__ s101)
{
  int j = blockIdx.x * blockDim.x + threadIdx.x;
  int level, span, idx; int* out;
  if (j < 2048)      { level = 100; span = 4096; out = s100; idx = j; }
  else if (j < 6144) { level = 101; span = 2048; out = s101; idx = j - 2048; }
  else return;
  // fold_in(key(42)=[0,42], level) = threefry2x32(key, (0, level))  [unchanged by partitionable]
  uint32_t r0, r1; tf2x32(0u, 42u, 0u, (uint32_t)level, r0, r1);
  // partitionable (fold-like) split: k_i = threefry2x32(key, (0, i)); randint uses k2 = row 1
  uint32_t k20, k21; tf2x32(r0, r1, 0u, 1u, k20, k21);
  // partitionable random_bits (32-bit): bits_i = o0 ^ o1 of threefry2x32(k2, (hi32(i)=0, lo32(i)=i))
  uint32_t o0, o1; tf2x32(k20, k21, 0u, (uint32_t)idx, o0, o1);
  uint32_t bits = o0 ^ o1;
  // randint with power-of-two span: multiplier = 2^32 % span = 0 -> lower_bits % span
  out[idx] = (int)(bits % (uint32_t)span);
}

// ---------------- 3. stable counting sort (argsort by hash) ----------------
__global__ __launch_bounds__(64) void sort_kernel(
    const int* __restrict__ hq, const int* __restrict__ hk,
    int* __restrict__ q100, int* __restrict__ k100,
    int* __restrict__ q101, int* __restrict__ k101)
{
  __shared__ unsigned short hist[64][128];
  __shared__ unsigned int   off [64][128];
  __shared__ int bstart[128];
  const int bid = blockIdx.x, t = threadIdx.x;
  const int* src; int n, base; int* out;
  if (bid < 8)       { int h = bid;     src = hq + h*NSEQ + 4096;          n = 4096; base = 4096;          out = q100 + h*4096; }
  else if (bid < 16) { int h = bid - 8; src = hk + h*NSEQ;                 n = 4096; base = 0;             out = k100 + h*4096; }
  else if (bid < 32) { int id = bid-16; int h = id>>1, p = id&1;
                       src = hq + h*NSEQ + p*4096 + 2048;                  n = 2048; base = p*4096 + 2048; out = q101 + id*2048; }
  else               { int id = bid-32; int h = id>>1, p = id&1;
                       src = hk + h*NSEQ + p*4096;                         n = 2048; base = p*4096;       out = k101 + id*2048; }
  const int chunk = n >> 6;
  for (int b = 0; b < 128; ++b) hist[t][b] = 0;
  __syncthreads();
  const int* mysrc = src + t * chunk;
  for (int i = 0; i < chunk; ++i) hist[t][mysrc[i]]++;
  __syncthreads();
  for (int bb = t; bb < 128; bb += 64){
    int s = 0;
    for (int tt = 0; tt < 64; ++tt) s += hist[tt][bb];
    bstart[bb] = s;
  }
  __syncthreads();
  if (t == 0){
    int run = 0;
    for (int b = 0; b < 128; ++b){ int c = bstart[b]; bstart[b] = run; run += c; }
  }
  __syncthreads();
  for (int bb = t; bb < 128; bb += 64){
    unsigned int run = bstart[bb];
    for (int tt = 0; tt < 64; ++tt){ off[tt][bb] = run; run += hist[tt][bb]; }
  }
  __syncthreads();
  for (int i = 0; i < chunk; ++i){
    int hsh = mysrc[i];
    unsigned int pos = off[t][hsh]++;
    out[pos] = base + t * chunk + i;   // stable: original order within bucket
  }
}

// ---------------- 4. diagonal causal flash attention (2048 blocks) ----------------
__global__ __launch_bounds__(256) void diag_kernel(
    const float* __restrict__ q, const float* __restrict__ k,
    const float* __restrict__ v, float* __restrict__ out, float* __restrict__ lse)
{
  const int bid = blockIdx.x;
  const int qt = bid & 31;          // 32 q tiles of 64 rows
  const int inst = bid >> 5;        // 0..31 = h*4 + tblk
  const int h = inst >> 2, tblk = inst & 3;
  const size_t hoff = (size_t)h * NSEQ * D;
  const int tid = threadIdx.x;
  const int r = tid >> 2, quad = tid & 3;
  const int blkbase = tblk * 2048;

  __shared__ float ks[64][68];
  __shared__ float vs[64][68];
  __shared__ float ps[64][65];

  float4 qreg[16];
  {
    const float4* qp = (const float4*)(q + hoff + (size_t)(blkbase + qt*64 + r) * D);
#pragma unroll
    for (int i = 0; i < 16; ++i) qreg[i] = qp[i];
  }
  float4 acc[4];
#pragma unroll
  for (int j = 0; j < 4; ++j) acc[j] = make_float4(0,0,0,0);
  float m = -INFINITY, l = 0.0f;
  const int qpos = qt*64 + r;

  for (int kt = 0; kt <= qt; ++kt){
    __syncthreads();
    {
      const float4* kp = (const float4*)(k + hoff + (size_t)(blkbase + kt*64 + r) * D + quad*16);
      const float4* vp = (const float4*)(v + hoff + (size_t)(blkbase + kt*64 + r) * D + quad*16);
      float4* kd = (float4*)&ks[r][quad*16];
      float4* vd = (float4*)&vs[r][quad*16];
#pragma unroll
      for (int j = 0; j < 4; ++j){ kd[j] = kp[j]; vd[j] = vp[j]; }
    }
    __syncthreads();
    float s[16];
    float tmax = -INFINITY;
#pragma unroll
    for (int i = 0; i < 16; ++i){
      const int kk = quad*16 + i;
      const float4* kp = (const float4*)&ks[kk][0];
      float dacc = 0.0f;
#pragma unroll
      for (int d4 = 0; d4 < 16; ++d4){
        float4 kv = kp[d4], qv = qreg[d4];
        dacc = fmaf(qv.x, kv.x, dacc); dacc = fmaf(qv.y, kv.y, dacc);
        dacc = fmaf(qv.z, kv.z, dacc); dacc = fmaf(qv.w, kv.w, dacc);
      }
      const int kpos = kt*64 + kk;
      s[i] = (kpos <= qpos) ? dacc * SCALE : -INFINITY;
      tmax = fmaxf(tmax, s[i]);
    }
    tmax = fmaxf(tmax, __shfl_xor(tmax, 1));
    tmax = fmaxf(tmax, __shfl_xor(tmax, 2));
    const float mnew = fmaxf(m, tmax);
    const float corr = __expf(m - mnew);
    float tsum = 0.0f;
#pragma unroll
    for (int i = 0; i < 16; ++i){
      float p = __expf(s[i] - mnew);
      ps[r][quad*16 + i] = p;
      tsum += p;
    }
    tsum += __shfl_xor(tsum, 1);
    tsum += __shfl_xor(tsum, 2);
    l = l * corr + tsum;
    m = mnew;
#pragma unroll
    for (int j = 0; j < 4; ++j) acc[j] = f4scale(acc[j], corr);
    __syncthreads();
#pragma unroll 4
    for (int kk = 0; kk < 64; ++kk){
      const float p = ps[r][kk];
      const float4* vp = (const float4*)&vs[kk][quad*16];
      f4fma(acc[0], p, vp[0]); f4fma(acc[1], p, vp[1]);
      f4fma(acc[2], p, vp[2]); f4fma(acc[3], p, vp[3]);
    }
  }
  const float invl = 1.0f / l;
  float4* op = (float4*)(out + hoff + (size_t)(blkbase + qt*64 + r) * D + quad*16);
#pragma unroll
  for (int j = 0; j < 4; ++j) op[j] = f4scale(acc[j], invl);
  if (quad == 0) lse[h*NSEQ + blkbase + qt*64 + r] = m + logf(l);
}

// ---------------- 5/6. LSH no-causal + merge (level 101 / 100) ----------------
template<int LEVEL>
__global__ __launch_bounds__(256) void nc_kernel(
    const float* __restrict__ q, const float* __restrict__ k,
    const float* __restrict__ v, float* __restrict__ out, float* __restrict__ lse,
    const int* __restrict__ qidx, const int* __restrict__ kidx, const int* __restrict__ samp)
{
  const int bid = blockIdx.x;
  int inst, jb;
  float delta;
  const int *qi, *ki, *sp;
  if (LEVEL == 101){
    inst = bid >> 5; jb = bid & 31;                 // 16 inst x 32 blocks(64 rows)
    delta = 2.0794415416798357f;                    // log(2048/256)
    qi = qidx + inst*2048; ki = kidx + inst*2048; sp = samp + inst*256;
  } else {
    inst = bid >> 6; jb = bid & 63;                 // 8 inst x 64 blocks
    delta = 2.772588722239781f;                     // log(4096/256)
    qi = qidx + inst*4096; ki = kidx + inst*4096; sp = samp + inst*256;
  }
  const int h = (LEVEL == 101) ? (inst >> 1) : inst;
  const int qb = jb >> 2;                           // sorted 256-block index
  const int tid = threadIdx.x;
  const int r = tid >> 2, quad = tid & 3;
  const size_t hoff = (size_t)h * NSEQ * D;

  __shared__ float ks[64][68];
  __shared__ float vs[64][68];
  __shared__ float ps[64][65];
  __shared__ int kmask[64];

  const int orig = qi[jb*64 + r];                   // within-head original row
  float4 qreg[16];
  {
    const float4* qp = (const float4*)(q + hoff + (size_t)orig * D);
#pragma unroll
    for (int i = 0; i < 16; ++i) qreg[i] = qp[i];
  }
  float4 acc[4];
#pragma unroll
  for (int j = 0; j < 4; ++j) acc[j] = make_float4(0,0,0,0);
  float m = -INFINITY, l = 0.0f;

  for (int kt = 0; kt < 8; ++kt){
    __syncthreads();
    {
      int krow, msk = 0;
      if (kt < 4){
        krow = ki[qb*256 + kt*64 + r];
      } else {
        int sidx = sp[(kt-4)*64 + r];
        krow = ki[sidx];
        msk = ((sidx >> 8) == qb) ? 1 : 0;
      }
      if (quad == 0) kmask[r] = msk;
      const float4* kp = (const float4*)(k + hoff + (size_t)krow * D + quad*16);
      const float4* vp = (const float4*)(v + hoff + (size_t)krow * D + quad*16);
      float4* kd = (float4*)&ks[r][quad*16];
      float4* vd = (float4*)&vs[r][quad*16];
#pragma unroll
      for (int j = 0; j < 4; ++j){ kd[j] = kp[j]; vd[j] = vp[j]; }
    }
    __syncthreads();
    const bool sampled_tile = (kt >= 4);
    float s[16];
    float tmax = -INFINITY;
#pragma unroll
    for (int i = 0; i < 16; ++i){
      const int kk = quad*16 + i;
      const float4* kp = (const float4*)&ks[kk][0];
      float dacc = 0.0f;
#pragma unroll
      for (int d4 = 0; d4 < 16; ++d4){
        float4 kv = kp[d4], qv = qreg[d4];
        dacc = fmaf(qv.x, kv.x, dacc); dacc = fmaf(qv.y, kv.y, dacc);
        dacc = fmaf(qv.z, kv.z, dacc); dacc = fmaf(qv.w, kv.w, dacc);
      }
      float val = dacc * SCALE;
      if (sampled_tile){
        val += delta;
        if (kmask[kk]) val = -INFINITY;
      }
      s[i] = val;
      tmax = fmaxf(tmax, val);
    }
    tmax = fmaxf(tmax, __shfl_xor(tmax, 1));
    tmax = fmaxf(tmax, __shfl_xor(tmax, 2));
    const float mnew = fmaxf(m, tmax);
    const float corr = __expf(m - mnew);
    float tsum = 0.0f;
#pragma unroll
    for (int i = 0; i < 16; ++i){
      float p = __expf(s[i] - mnew);
      ps[r][quad*16 + i] = p;
      tsum += p;
    }
    tsum += __shfl_xor(tsum, 1);
    tsum += __shfl_xor(tsum, 2);
    l = l * corr + tsum;
    m = mnew;
#pragma unroll
    for (int j = 0; j < 4; ++j) acc[j] = f4scale(acc[j], corr);
    __syncthreads();
#pragma unroll 4
    for (int kk = 0; kk < 64; ++kk){
      const float p = ps[r][kk];
      const float4* vp = (const float4*)&vs[kk][quad*16];
      f4fma(acc[0], p, vp[0]); f4fma(acc[1], p, vp[1]);
      f4fma(acc[2], p, vp[2]); f4fma(acc[3], p, vp[3]);
    }
  }
  // merge with existing (diag / previous level) result via _add_attn
  const float l2 = m + logf(l);
  const float invl = 1.0f / l;
  const float l1 = lse[h*NSEQ + orig];
  const float c = 1.0f / (1.0f + __expf(l2 - l1));
  float4* op = (float4*)(out + hoff + (size_t)orig * D + quad*16);
#pragma unroll
  for (int j = 0; j < 4; ++j){
    float4 a1 = op[j];
    float4 a2 = f4scale(acc[j], invl);
    op[j] = make_float4(c*a1.x + (1.0f-c)*a2.x, c*a1.y + (1.0f-c)*a2.y,
                        c*a1.z + (1.0f-c)*a2.z, c*a1.w + (1.0f-c)*a2.w);
  }
  if (quad == 0) lse[h*NSEQ + orig] = l1 - logf(c + 1.1920928955078125e-07f);
}

// ---------------- launch ----------------
extern "C" void kernel_launch(void* const* d_in, const int* in_sizes, int n_in,
                              void* d_out, int out_size, void* d_ws, size_t ws_size,
                              hipStream_t stream)
{
  const float* q    = (const float*)d_in[0];
  const float* k    = (const float*)d_in[1];
  const float* v    = (const float*)d_in[2];
  const float* proj = (const float*)d_in[3];
  float* out = (float*)d_out;

  char* ws = (char*)d_ws;
  float* lse = (float*)ws;                 // 65536 f32
  int* hq   = (int*)(ws + 65536*4);        // 65536
  int* hk   = hq + 65536;                  // 65536
  int* q100 = hk + 65536;                  // 32768
  int* k100 = q100 + 32768;                // 32768
  int* q101 = k100 + 32768;                // 32768
  int* k101 = q101 + 32768;                // 32768
  int* s100 = k101 + 32768;                // 2048
  int* s101 = s100 + 2048;                 // 4096

  hash_kernel  <<<dim3(512),  dim3(256), 0, stream>>>(q, k, proj, hq, hk);
  sample_kernel<<<dim3(24),   dim3(256), 0, stream>>>(s100, s101);
  sort_kernel  <<<dim3(48),   dim3(64),  0, stream>>>(hq, hk, q100, k100, q101, k101);
  diag_kernel  <<<dim3(1024), dim3(256), 0, stream>>>(q, k, v, out, lse);
  nc_kernel<101><<<dim3(512), dim3(256), 0, stream>>>(q, k, v, out, lse, q101, k101, s101);
  nc_kernel<100><<<dim3(512), dim3(256), 0, stream>>>(q, k, v, out, lse, q100, k100, s100);
}

// Round 3
// 246.454 us; speedup vs baseline: 7.0894x; 7.0894x over previous
//
#include <hip/hip_runtime.h>
#include <stdint.h>
#include <math.h>

#define H 8
#define NSEQ 8192
#define D 64
#define SCALE 0.125f
#define EPSF 1.1920928955078125e-07f

typedef short v8s __attribute__((ext_vector_type(8)));
typedef float v4f __attribute__((ext_vector_type(4)));

#define MFMA16(a,b,c) __builtin_amdgcn_mfma_f32_16x16x32_bf16((a),(b),(c),0,0,0)
// swizzled LDS byte address: 128B row stride, XOR bank swizzle (G4 / m214)
#define SWZ(row, cb) (((row)*128) + ((cb) ^ ((((row)&7))<<4)))

__device__ __forceinline__ unsigned short f2bf(float f){
  union { float f; unsigned int u; } c; c.f = f;
  unsigned int u = c.u + 0x7FFFu + ((c.u >> 16) & 1u);   // RNE
  return (unsigned short)(u >> 16);
}

// ---------------- 1. LSH hash (Gray-coded sign bits) ----------------
__global__ __launch_bounds__(256) void hash_kernel(
    const float* __restrict__ q, const float* __restrict__ k,
    const float* __restrict__ proj, int* __restrict__ hq, int* __restrict__ hk)
{
  __shared__ float pj[448];
  for (int i = threadIdx.x; i < 448; i += blockDim.x) pj[i] = proj[i];
  __syncthreads();
  int idx = blockIdx.x * blockDim.x + threadIdx.x;
  if (idx >= 2 * H * NSEQ) return;
  int isk = idx >= H * NSEQ;
  int r = isk ? idx - H * NSEQ : idx;
  const float* src = (isk ? k : q) + (size_t)r * D;
  float dot[7] = {0,0,0,0,0,0,0};
  for (int d = 0; d < D; ++d){
    float x = src[d];
#pragma unroll
    for (int p = 0; p < 7; ++p) dot[p] = fmaf(x, pj[d*7+p], dot[p]);
  }
  int b = 0;
#pragma unroll
  for (int p = 0; p < 7; ++p) if (dot[p] > 0.0f) b |= (1 << p);
  int g = b ^ (b >> 1);
  (isk ? hk : hq)[r] = g;
}

// ---------------- 2. Threefry-2x32-20 sampled indices (partitionable PRNG) ----------------
__device__ __forceinline__ void tf2x32(uint32_t k0, uint32_t k1,
                                       uint32_t x0, uint32_t x1,
                                       uint32_t& o0, uint32_t& o1)
{
  uint32_t ks0 = k0, ks1 = k1, ks2 = k0 ^ k1 ^ 0x1BD11BDAu;
  x0 += ks0; x1 += ks1;
#define RND(r) { x0 += x1; x1 = (x1 << (r)) | (x1 >> (32-(r))); x1 ^= x0; }
  RND(13) RND(15) RND(26) RND(6)  x0 += ks1; x1 += ks2 + 1u;
  RND(17) RND(29) RND(16) RND(24) x0 += ks2; x1 += ks0 + 2u;
  RND(13) RND(15) RND(26) RND(6)  x0 += ks0; x1 += ks1 + 3u;
  RND(17) RND(29) RND(16) RND(24) x0 += ks1; x1 += ks2 + 4u;
  RND(13) RND(15) RND(26) RND(6)  x0 += ks2; x1 += ks0 + 5u;
#undef RND
  o0 = x0; o1 = x1;
}

__global__ __launch_bounds__(256) void sample_kernel(int* __restrict__ s100, int* __restrict__ s101)
{
  int j = blockIdx.x * blockDim.x + threadIdx.x;
  int level, span, idx; int* out;
  if (j < 2048)      { level = 100; span = 4096; out = s100; idx = j; }
  else if (j < 6144) { level = 101; span = 2048; out = s101; idx = j - 2048; }
  else return;
  uint32_t r0, r1; tf2x32(0u, 42u, 0u, (uint32_t)level, r0, r1);
  uint32_t k20, k21; tf2x32(r0, r1, 0u, 1u, k20, k21);
  uint32_t o0, o1; tf2x32(k20, k21, 0u, (uint32_t)idx, o0, o1);
  uint32_t bits = o0 ^ o1;
  out[idx] = (int)(bits % (uint32_t)span);
}

// ---------------- 3. stable counting sort (argsort by hash) ----------------
__global__ __launch_bounds__(64) void sort_kernel(
    const int* __restrict__ hq, const int* __restrict__ hk,
    int* __restrict__ q100, int* __restrict__ k100,
    int* __restrict__ q101, int* __restrict__ k101)
{
  __shared__ unsigned short hist[64][128];
  __shared__ unsigned int   off [64][128];
  __shared__ int bstart[128];
  const int bid = blockIdx.x, t = threadIdx.x;
  const int* src; int n, base; int* out;
  if (bid < 8)       { int h = bid;     src = hq + h*NSEQ + 4096;          n = 4096; base = 4096;          out = q100 + h*4096; }
  else if (bid < 16) { int h = bid - 8; src = hk + h*NSEQ;                 n = 4096; base = 0;             out = k100 + h*4096; }
  else if (bid < 32) { int id = bid-16; int h = id>>1, p = id&1;
                       src = hq + h*NSEQ + p*4096 + 2048;                  n = 2048; base = p*4096 + 2048; out = q101 + id*2048; }
  else               { int id = bid-32; int h = id>>1, p = id&1;
                       src = hk + h*NSEQ + p*4096;                         n = 2048; base = p*4096;       out = k101 + id*2048; }
  const int chunk = n >> 6;
  for (int b = 0; b < 128; ++b) hist[t][b] = 0;
  __syncthreads();
  const int* mysrc = src + t * chunk;
  for (int i = 0; i < chunk; ++i) hist[t][mysrc[i]]++;
  __syncthreads();
  for (int bb = t; bb < 128; bb += 64){
    int s = 0;
    for (int tt = 0; tt < 64; ++tt) s += hist[tt][bb];
    bstart[bb] = s;
  }
  __syncthreads();
  if (t == 0){
    int run = 0;
    for (int b = 0; b < 128; ++b){ int c = bstart[b]; bstart[b] = run; run += c; }
  }
  __syncthreads();
  for (int bb = t; bb < 128; bb += 64){
    unsigned int run = bstart[bb];
    for (int tt = 0; tt < 64; ++tt){ off[tt][bb] = run; run += hist[tt][bb]; }
  }
  __syncthreads();
  for (int i = 0; i < chunk; ++i){
    int hsh = mysrc[i];
    unsigned int pos = off[t][hsh]++;
    out[pos] = base + t * chunk + i;
  }
}

// ================= MFMA flash attention cores =================
// Block: 128 threads = 2 waves; wave handles 32 q rows (2 M-subtiles of 16).
// K tile: 64 keys. LDS: K[64][64]bf16 swizzled, VT[64][64]bf16 swizzled, P per wave [32][64]bf16 swizzled.

// ---------------- 4. diagonal causal (paired q-tiles for balance) ----------------
__global__ __launch_bounds__(128) void diag_mfma(
    const float* __restrict__ q, const float* __restrict__ k,
    const float* __restrict__ v, float* __restrict__ out, float* __restrict__ lse)
{
  __shared__ __align__(16) char Ks[8192];
  __shared__ __align__(16) char VTs[8192];
  __shared__ __align__(16) char Ps[2][4096];
  const int bid = blockIdx.x;
  const int inst = bid >> 4;          // 32 instances (h*4 + tblk)
  const int pi  = bid & 15;           // pair index
  const int h = inst >> 2, tblk = inst & 3;
  const size_t hoff = (size_t)h * NSEQ * D;
  const float* qh = q + hoff; const float* kh = k + hoff; const float* vh = v + hoff;
  const int blkbase = tblk * 2048;
  const int tid = threadIdx.x;
  const int wid = tid >> 6, lane = tid & 63;
  const int lo = lane & 15, hi = lane >> 4;
  char* Pw = Ps[wid];
  const int sr = tid >> 1, sh = tid & 1;      // K staging: row, half
  const int rp = tid >> 2, cg = tid & 3;      // VT staging: row-pair, col group

  const int qts[2] = { pi, 31 - pi };
#pragma unroll 1
  for (int sel = 0; sel < 2; ++sel){
    const int qt = qts[sel];
    const int qbase = blkbase + qt*64 + wid*32;
    v8s qf[2][2];
#pragma unroll
    for (int qsub = 0; qsub < 2; ++qsub){
      const float* qrow = qh + (size_t)(qbase + qsub*16 + lo) * D;
#pragma unroll
      for (int kc = 0; kc < 2; ++kc){
        float4 f0 = *(const float4*)(qrow + kc*32 + hi*8);
        float4 f1 = *(const float4*)(qrow + kc*32 + hi*8 + 4);
        union { unsigned short u[8]; v8s v; } pk;
        pk.u[0]=f2bf(f0.x); pk.u[1]=f2bf(f0.y); pk.u[2]=f2bf(f0.z); pk.u[3]=f2bf(f0.w);
        pk.u[4]=f2bf(f1.x); pk.u[5]=f2bf(f1.y); pk.u[6]=f2bf(f1.z); pk.u[7]=f2bf(f1.w);
        qf[qsub][kc] = pk.v;
      }
    }
    v4f oacc[2][4];
    float mrow[2][4], lrow[2][4];
    const v4f vzero = {0.0f, 0.0f, 0.0f, 0.0f};
#pragma unroll
    for (int a = 0; a < 2; ++a)
#pragma unroll
      for (int b = 0; b < 4; ++b){ oacc[a][b] = vzero; mrow[a][b] = -INFINITY; lrow[a][b] = 0.0f; }

#pragma unroll 1
    for (int kt = 0; kt <= qt; ++kt){
      __syncthreads();
      { // stage K (bf16, swizzled)
        const float* src = kh + (size_t)(blkbase + kt*64 + sr)*D + sh*32;
        union { unsigned short u[32]; uint4 q4[4]; } t;
#pragma unroll
        for (int i = 0; i < 8; ++i){
          float4 f = *(const float4*)(src + i*4);
          t.u[i*4+0]=f2bf(f.x); t.u[i*4+1]=f2bf(f.y); t.u[i*4+2]=f2bf(f.z); t.u[i*4+3]=f2bf(f.w);
        }
#pragma unroll
        for (int j = 0; j < 4; ++j)
          *(uint4*)(Ks + SWZ(sr, sh*64 + j*16)) = t.q4[j];
      }
      { // stage V transposed (packed k-pairs)
        const float* s0 = vh + (size_t)(blkbase + kt*64 + 2*rp)*D + cg*16;
        const float* s1 = s0 + D;
        float a0[16], a1[16];
#pragma unroll
        for (int i = 0; i < 4; ++i){
          *(float4*)(a0 + i*4) = *(const float4*)(s0 + i*4);
          *(float4*)(a1 + i*4) = *(const float4*)(s1 + i*4);
        }
#pragma unroll
        for (int j = 0; j < 16; ++j){
          int c = cg*16 + j;
          unsigned int pkv = (unsigned int)f2bf(a0[j]) | ((unsigned int)f2bf(a1[j]) << 16);
          *(unsigned int*)(VTs + SWZ(c, rp*4)) = pkv;
        }
      }
      __syncthreads();
      // QK^T
      v4f sacc[2][4];
#pragma unroll
      for (int a = 0; a < 2; ++a)
#pragma unroll
        for (int st = 0; st < 4; ++st) sacc[a][st] = vzero;
#pragma unroll
      for (int st = 0; st < 4; ++st){
#pragma unroll
        for (int kc = 0; kc < 2; ++kc){
          v8s bf = *(v8s*)(Ks + SWZ(st*16 + lo, kc*64 + hi*16));
          sacc[0][st] = MFMA16(qf[0][kc], bf, sacc[0][st]);
          sacc[1][st] = MFMA16(qf[1][kc], bf, sacc[1][st]);
        }
      }
      const bool lastt = (kt == qt);
#pragma unroll
      for (int qsub = 0; qsub < 2; ++qsub)
#pragma unroll
        for (int st = 0; st < 4; ++st)
#pragma unroll
          for (int reg = 0; reg < 4; ++reg){
            float val = sacc[qsub][st][reg] * SCALE;
            if (lastt){
              int qpl = wid*32 + qsub*16 + hi*4 + reg;
              int kpl = st*16 + lo;
              if (kpl > qpl) val = -INFINITY;
            }
            sacc[qsub][st][reg] = val;
          }
      // online softmax + P write
#pragma unroll
      for (int qsub = 0; qsub < 2; ++qsub){
#pragma unroll
        for (int reg = 0; reg < 4; ++reg){
          float tm = fmaxf(fmaxf(sacc[qsub][0][reg], sacc[qsub][1][reg]),
                           fmaxf(sacc[qsub][2][reg], sacc[qsub][3][reg]));
          tm = fmaxf(tm, __shfl_xor(tm, 1));
          tm = fmaxf(tm, __shfl_xor(tm, 2));
          tm = fmaxf(tm, __shfl_xor(tm, 4));
          tm = fmaxf(tm, __shfl_xor(tm, 8));
          float mn = fmaxf(mrow[qsub][reg], tm);
          float corr = __expf(mrow[qsub][reg] - mn);
          mrow[qsub][reg] = mn;
          int qr = qsub*16 + hi*4 + reg;
          float ts = 0.0f;
#pragma unroll
          for (int st = 0; st < 4; ++st){
            float p = __expf(sacc[qsub][st][reg] - mn);
            ts += p;
            *(unsigned short*)(Pw + SWZ(qr, (st*16 + lo)*2)) = f2bf(p);
          }
          ts += __shfl_xor(ts, 1);
          ts += __shfl_xor(ts, 2);
          ts += __shfl_xor(ts, 4);
          ts += __shfl_xor(ts, 8);
          lrow[qsub][reg] = lrow[qsub][reg] * corr + ts;
#pragma unroll
          for (int dt = 0; dt < 4; ++dt)
            oacc[qsub][dt][reg] *= corr;
        }
      }
      asm volatile("" ::: "memory");   // order P writes before PV reads (same wave)
      // PV
#pragma unroll
      for (int kc = 0; kc < 2; ++kc){
        v8s pa0 = *(v8s*)(Pw + SWZ(lo,      kc*64 + hi*16));
        v8s pa1 = *(v8s*)(Pw + SWZ(16 + lo, kc*64 + hi*16));
#pragma unroll
        for (int dt = 0; dt < 4; ++dt){
          v8s vb = *(v8s*)(VTs + SWZ(dt*16 + lo, kc*64 + hi*16));
          oacc[0][dt] = MFMA16(pa0, vb, oacc[0][dt]);
          oacc[1][dt] = MFMA16(pa1, vb, oacc[1][dt]);
        }
      }
    } // kt
    // epilogue
#pragma unroll
    for (int qsub = 0; qsub < 2; ++qsub)
#pragma unroll
      for (int reg = 0; reg < 4; ++reg){
        int qrow = qbase + qsub*16 + hi*4 + reg;
        float inv = 1.0f / lrow[qsub][reg];
#pragma unroll
        for (int dt = 0; dt < 4; ++dt)
          out[hoff + (size_t)qrow*D + dt*16 + lo] = oacc[qsub][dt][reg] * inv;
        if (lo == 0) lse[h*NSEQ + qrow] = mrow[qsub][reg] + logf(lrow[qsub][reg]);
      }
  } // sel
}

// ---------------- 5/6. LSH no-causal + merge (level 101 / 100) ----------------
template<int LEVEL>
__global__ __launch_bounds__(128) void nc_mfma(
    const float* __restrict__ q, const float* __restrict__ k,
    const float* __restrict__ v, float* __restrict__ out, float* __restrict__ lse,
    const int* __restrict__ qidx, const int* __restrict__ kidx, const int* __restrict__ samp)
{
  __shared__ __align__(16) char Ks[8192];
  __shared__ __align__(16) char VTs[8192];
  __shared__ __align__(16) char Ps[2][4096];
  __shared__ int kmk[64];
  const int bid = blockIdx.x;
  int inst, jb; float delta;
  const int *qi, *ki, *sp;
  if (LEVEL == 101){
    inst = bid >> 5; jb = bid & 31;
    delta = 2.0794415416798357f;                    // log(2048/256)
    qi = qidx + inst*2048; ki = kidx + inst*2048; sp = samp + inst*256;
  } else {
    inst = bid >> 6; jb = bid & 63;
    delta = 2.772588722239781f;                     // log(4096/256)
    qi = qidx + inst*4096; ki = kidx + inst*4096; sp = samp + inst*256;
  }
  const int h = (LEVEL == 101) ? (inst >> 1) : inst;
  const int qb = jb >> 2;
  const size_t hoff = (size_t)h * NSEQ * D;
  const float* qh = q + hoff; const float* kh = k + hoff; const float* vh = v + hoff;
  const int tid = threadIdx.x;
  const int wid = tid >> 6, lane = tid & 63;
  const int lo = lane & 15, hi = lane >> 4;
  char* Pw = Ps[wid];
  const int sr = tid >> 1, sh = tid & 1;
  const int rp = tid >> 2, cg = tid & 3;

  int orig[2][4];
  v8s qf[2][2];
#pragma unroll
  for (int qsub = 0; qsub < 2; ++qsub){
    int qrowi = qi[jb*64 + wid*32 + qsub*16 + lo];
    const float* qrow = qh + (size_t)qrowi * D;
#pragma unroll
    for (int kc = 0; kc < 2; ++kc){
      float4 f0 = *(const float4*)(qrow + kc*32 + hi*8);
      float4 f1 = *(const float4*)(qrow + kc*32 + hi*8 + 4);
      union { unsigned short u[8]; v8s v; } pk;
      pk.u[0]=f2bf(f0.x); pk.u[1]=f2bf(f0.y); pk.u[2]=f2bf(f0.z); pk.u[3]=f2bf(f0.w);
      pk.u[4]=f2bf(f1.x); pk.u[5]=f2bf(f1.y); pk.u[6]=f2bf(f1.z); pk.u[7]=f2bf(f1.w);
      qf[qsub][kc] = pk.v;
    }
#pragma unroll
    for (int reg = 0; reg < 4; ++reg)
      orig[qsub][reg] = qi[jb*64 + wid*32 + qsub*16 + hi*4 + reg];
  }
  v4f oacc[2][4];
  float mrow[2][4], lrow[2][4];
  const v4f vzero = {0.0f, 0.0f, 0.0f, 0.0f};
#pragma unroll
  for (int a = 0; a < 2; ++a)
#pragma unroll
    for (int b = 0; b < 4; ++b){ oacc[a][b] = vzero; mrow[a][b] = -INFINITY; lrow[a][b] = 0.0f; }

#pragma unroll 1
  for (int kt = 0; kt < 8; ++kt){
    __syncthreads();
    { // stage K
      int krow; int msk = 0;
      if (kt < 4) krow = ki[qb*256 + kt*64 + sr];
      else { int sidx = sp[(kt-4)*64 + sr]; krow = ki[sidx]; msk = ((sidx >> 8) == qb) ? 1 : 0; }
      if (sh == 0) kmk[sr] = msk;
      const float* src = kh + (size_t)krow*D + sh*32;
      union { unsigned short u[32]; uint4 q4[4]; } t;
#pragma unroll
      for (int i = 0; i < 8; ++i){
        float4 f = *(const float4*)(src + i*4);
        t.u[i*4+0]=f2bf(f.x); t.u[i*4+1]=f2bf(f.y); t.u[i*4+2]=f2bf(f.z); t.u[i*4+3]=f2bf(f.w);
      }
#pragma unroll
      for (int j = 0; j < 4; ++j)
        *(uint4*)(Ks + SWZ(sr, sh*64 + j*16)) = t.q4[j];
    }
    { // stage VT
      int k0 = 2*rp, k1 = 2*rp + 1;
      int g0, g1;
      if (kt < 4){ g0 = ki[qb*256 + kt*64 + k0]; g1 = ki[qb*256 + kt*64 + k1]; }
      else       { g0 = ki[sp[(kt-4)*64 + k0]];  g1 = ki[sp[(kt-4)*64 + k1]]; }
      const float* s0 = vh + (size_t)g0*D + cg*16;
      const float* s1 = vh + (size_t)g1*D + cg*16;
      float a0[16], a1[16];
#pragma unroll
      for (int i = 0; i < 4; ++i){
        *(float4*)(a0 + i*4) = *(const float4*)(s0 + i*4);
        *(float4*)(a1 + i*4) = *(const float4*)(s1 + i*4);
      }
#pragma unroll
      for (int j = 0; j < 16; ++j){
        int c = cg*16 + j;
        unsigned int pkv = (unsigned int)f2bf(a0[j]) | ((unsigned int)f2bf(a1[j]) << 16);
        *(unsigned int*)(VTs + SWZ(c, rp*4)) = pkv;
      }
    }
    __syncthreads();
    const bool sampled = (kt >= 4);
    int km[4] = {0,0,0,0};
    if (sampled){ km[0]=kmk[lo]; km[1]=kmk[16+lo]; km[2]=kmk[32+lo]; km[3]=kmk[48+lo]; }
    // QK^T
    v4f sacc[2][4];
#pragma unroll
    for (int a = 0; a < 2; ++a)
#pragma unroll
      for (int st = 0; st < 4; ++st) sacc[a][st] = vzero;
#pragma unroll
    for (int st = 0; st < 4; ++st){
#pragma unroll
      for (int kc = 0; kc < 2; ++kc){
        v8s bf = *(v8s*)(Ks + SWZ(st*16 + lo, kc*64 + hi*16));
        sacc[0][st] = MFMA16(qf[0][kc], bf, sacc[0][st]);
        sacc[1][st] = MFMA16(qf[1][kc], bf, sacc[1][st]);
      }
    }
#pragma unroll
    for (int qsub = 0; qsub < 2; ++qsub)
#pragma unroll
      for (int st = 0; st < 4; ++st)
#pragma unroll
        for (int reg = 0; reg < 4; ++reg){
          float val = sacc[qsub][st][reg] * SCALE;
          if (sampled){ val += delta; if (km[st]) val = -INFINITY; }
          sacc[qsub][st][reg] = val;
        }
    // online softmax + P write
#pragma unroll
    for (int qsub = 0; qsub < 2; ++qsub){
#pragma unroll
      for (int reg = 0; reg < 4; ++reg){
        float tm = fmaxf(fmaxf(sacc[qsub][0][reg], sacc[qsub][1][reg]),
                         fmaxf(sacc[qsub][2][reg], sacc[qsub][3][reg]));
        tm = fmaxf(tm, __shfl_xor(tm, 1));
        tm = fmaxf(tm, __shfl_xor(tm, 2));
        tm = fmaxf(tm, __shfl_xor(tm, 4));
        tm = fmaxf(tm, __shfl_xor(tm, 8));
        float mn = fmaxf(mrow[qsub][reg], tm);
        float corr = __expf(mrow[qsub][reg] - mn);
        mrow[qsub][reg] = mn;
        int qr = qsub*16 + hi*4 + reg;
        float ts = 0.0f;
#pragma unroll
        for (int st = 0; st < 4; ++st){
          float p = __expf(sacc[qsub][st][reg] - mn);
          ts += p;
          *(unsigned short*)(Pw + SWZ(qr, (st*16 + lo)*2)) = f2bf(p);
        }
        ts += __shfl_xor(ts, 1);
        ts += __shfl_xor(ts, 2);
        ts += __shfl_xor(ts, 4);
        ts += __shfl_xor(ts, 8);
        lrow[qsub][reg] = lrow[qsub][reg] * corr + ts;
#pragma unroll
        for (int dt = 0; dt < 4; ++dt)
          oacc[qsub][dt][reg] *= corr;
      }
    }
    asm volatile("" ::: "memory");
    // PV
#pragma unroll
    for (int kc = 0; kc < 2; ++kc){
      v8s pa0 = *(v8s*)(Pw + SWZ(lo,      kc*64 + hi*16));
      v8s pa1 = *(v8s*)(Pw + SWZ(16 + lo, kc*64 + hi*16));
#pragma unroll
      for (int dt = 0; dt < 4; ++dt){
        v8s vb = *(v8s*)(VTs + SWZ(dt*16 + lo, kc*64 + hi*16));
        oacc[0][dt] = MFMA16(pa0, vb, oacc[0][dt]);
        oacc[1][dt] = MFMA16(pa1, vb, oacc[1][dt]);
      }
    }
  } // kt
  // merge epilogue (_add_attn)
#pragma unroll
  for (int qsub = 0; qsub < 2; ++qsub)
#pragma unroll
    for (int reg = 0; reg < 4; ++reg){
      int og = orig[qsub][reg];
      float l1 = lse[h*NSEQ + og];
      float l2v = mrow[qsub][reg] + logf(lrow[qsub][reg]);
      float c = 1.0f / (1.0f + __expf(l2v - l1));
      float inv = (1.0f - c) / lrow[qsub][reg];
#pragma unroll
      for (int dt = 0; dt < 4; ++dt){
        float* ap = out + hoff + (size_t)og*D + dt*16 + lo;
        *ap = c * (*ap) + inv * oacc[qsub][dt][reg];
      }
      if (lo == 0) lse[h*NSEQ + og] = l1 - logf(c + EPSF);
    }
}

// ---------------- launch ----------------
extern "C" void kernel_launch(void* const* d_in, const int* in_sizes, int n_in,
                              void* d_out, int out_size, void* d_ws, size_t ws_size,
                              hipStream_t stream)
{
  const float* q    = (const float*)d_in[0];
  const float* k    = (const float*)d_in[1];
  const float* v    = (const float*)d_in[2];
  const float* proj = (const float*)d_in[3];
  float* out = (float*)d_out;

  char* ws = (char*)d_ws;
  float* lse = (float*)ws;                 // 65536 f32
  int* hq   = (int*)(ws + 65536*4);        // 65536
  int* hk   = hq + 65536;                  // 65536
  int* q100 = hk + 65536;                  // 32768
  int* k100 = q100 + 32768;                // 32768
  int* q101 = k100 + 32768;                // 32768
  int* k101 = q101 + 32768;                // 32768
  int* s100 = k101 + 32768;                // 2048
  int* s101 = s100 + 2048;                 // 4096

  hash_kernel  <<<dim3(512),  dim3(256), 0, stream>>>(q, k, proj, hq, hk);
  sample_kernel<<<dim3(24),   dim3(256), 0, stream>>>(s100, s101);
  sort_kernel  <<<dim3(48),   dim3(64),  0, stream>>>(hq, hk, q100, k100, q101, k101);
  diag_mfma    <<<dim3(512),  dim3(128), 0, stream>>>(q, k, v, out, lse);
  nc_mfma<101> <<<dim3(512),  dim3(128), 0, stream>>>(q, k, v, out, lse, q101, k101, s101);
  nc_mfma<100> <<<dim3(512),  dim3(128), 0, stream>>>(q, k, v, out, lse, q100, k100, s100);
}

// Round 4
// 180.132 us; speedup vs baseline: 9.6996x; 1.3682x over previous
//
#include <hip/hip_runtime.h>
#include <stdint.h>
#include <math.h>

#define H 8
#define NSEQ 8192
#define D 64
#define SCALE 0.125f
#define EPSF 1.1920928955078125e-07f

typedef short v8s __attribute__((ext_vector_type(8)));
typedef float v4f __attribute__((ext_vector_type(4)));
typedef unsigned short ushort_t;

#define MFMA16(a,b,c) __builtin_amdgcn_mfma_f32_16x16x32_bf16((a),(b),(c),0,0,0)
// swizzled LDS byte address: 128B row stride, XOR bank swizzle (G4)
#define SWZ(row, cb) (((row)*128) + ((cb) ^ ((((row)&7))<<4)))

__device__ __forceinline__ ushort_t f2bf(float f){
  union { float f; unsigned int u; } c; c.f = f;
  unsigned int u = c.u + 0x7FFFu + ((c.u >> 16) & 1u);   // RNE
  return (ushort_t)(u >> 16);
}

// ---------------- 0. bf16 prepass: Q,K,V fp32 -> bf16 ----------------
__global__ __launch_bounds__(256) void prep_kernel(
    const float* __restrict__ q, const float* __restrict__ k, const float* __restrict__ v,
    ushort_t* __restrict__ qb, ushort_t* __restrict__ kb, ushort_t* __restrict__ vb)
{
  int gid = blockIdx.x * 256 + threadIdx.x;          // 3 * 524288 threads
  int tensor = gid >> 19;
  size_t off = (size_t)(gid & 524287) * 8;
  const float* src = tensor == 0 ? q : (tensor == 1 ? k : v);
  ushort_t* dst = tensor == 0 ? qb : (tensor == 1 ? kb : vb);
  float4 f0 = *(const float4*)(src + off);
  float4 f1 = *(const float4*)(src + off + 4);
  uint4 o;
  o.x = (unsigned int)f2bf(f0.x) | ((unsigned int)f2bf(f0.y) << 16);
  o.y = (unsigned int)f2bf(f0.z) | ((unsigned int)f2bf(f0.w) << 16);
  o.z = (unsigned int)f2bf(f1.x) | ((unsigned int)f2bf(f1.y) << 16);
  o.w = (unsigned int)f2bf(f1.z) | ((unsigned int)f2bf(f1.w) << 16);
  *(uint4*)(dst + off) = o;
}

// ---------------- 1. LSH hash (fp32, same fmaf order as before; float4 loads) ----------------
__global__ __launch_bounds__(256) void hash_kernel(
    const float* __restrict__ q, const float* __restrict__ k,
    const float* __restrict__ proj, int* __restrict__ hq, int* __restrict__ hk)
{
  __shared__ float pj[448];
  for (int i = threadIdx.x; i < 448; i += blockDim.x) pj[i] = proj[i];
  __syncthreads();
  int idx = blockIdx.x * blockDim.x + threadIdx.x;
  if (idx >= 2 * H * NSEQ) return;
  int isk = idx >= H * NSEQ;
  int r = isk ? idx - H * NSEQ : idx;
  const float4* s4 = (const float4*)((isk ? k : q) + (size_t)r * D);
  float dot[7] = {0,0,0,0,0,0,0};
#pragma unroll
  for (int d4 = 0; d4 < 16; ++d4){
    float4 x = s4[d4];
#pragma unroll
    for (int p = 0; p < 7; ++p) dot[p] = fmaf(x.x, pj[(d4*4+0)*7+p], dot[p]);
#pragma unroll
    for (int p = 0; p < 7; ++p) dot[p] = fmaf(x.y, pj[(d4*4+1)*7+p], dot[p]);
#pragma unroll
    for (int p = 0; p < 7; ++p) dot[p] = fmaf(x.z, pj[(d4*4+2)*7+p], dot[p]);
#pragma unroll
    for (int p = 0; p < 7; ++p) dot[p] = fmaf(x.w, pj[(d4*4+3)*7+p], dot[p]);
  }
  int b = 0;
#pragma unroll
  for (int p = 0; p < 7; ++p) if (dot[p] > 0.0f) b |= (1 << p);
  int g = b ^ (b >> 1);
  (isk ? hk : hq)[r] = g;
}

// ---------------- 2. Threefry-2x32-20 sampled indices (partitionable PRNG) ----------------
__device__ __forceinline__ void tf2x32(uint32_t k0, uint32_t k1,
                                       uint32_t x0, uint32_t x1,
                                       uint32_t& o0, uint32_t& o1)
{
  uint32_t ks0 = k0, ks1 = k1, ks2 = k0 ^ k1 ^ 0x1BD11BDAu;
  x0 += ks0; x1 += ks1;
#define RND(r) { x0 += x1; x1 = (x1 << (r)) | (x1 >> (32-(r))); x1 ^= x0; }
  RND(13) RND(15) RND(26) RND(6)  x0 += ks1; x1 += ks2 + 1u;
  RND(17) RND(29) RND(16) RND(24) x0 += ks2; x1 += ks0 + 2u;
  RND(13) RND(15) RND(26) RND(6)  x0 += ks0; x1 += ks1 + 3u;
  RND(17) RND(29) RND(16) RND(24) x0 += ks1; x1 += ks2 + 4u;
  RND(13) RND(15) RND(26) RND(6)  x0 += ks2; x1 += ks0 + 5u;
#undef RND
  o0 = x0; o1 = x1;
}

__global__ __launch_bounds__(256) void sample_kernel(int* __restrict__ s100, int* __restrict__ s101)
{
  int j = blockIdx.x * blockDim.x + threadIdx.x;
  int level, span, idx; int* out;
  if (j < 2048)      { level = 100; span = 4096; out = s100; idx = j; }
  else if (j < 6144) { level = 101; span = 2048; out = s101; idx = j - 2048; }
  else return;
  uint32_t r0, r1; tf2x32(0u, 42u, 0u, (uint32_t)level, r0, r1);
  uint32_t k20, k21; tf2x32(r0, r1, 0u, 1u, k20, k21);
  uint32_t o0, o1; tf2x32(k20, k21, 0u, (uint32_t)idx, o0, o1);
  uint32_t bits = o0 ^ o1;
  out[idx] = (int)(bits % (uint32_t)span);
}

// ---------------- 3. stable counting sort (argsort by hash) ----------------
__global__ __launch_bounds__(64) void sort_kernel(
    const int* __restrict__ hq, const int* __restrict__ hk,
    int* __restrict__ q100, int* __restrict__ k100,
    int* __restrict__ q101, int* __restrict__ k101)
{
  __shared__ unsigned short hist[64][128];
  __shared__ unsigned int   off [64][128];
  __shared__ int bstart[128];
  const int bid = blockIdx.x, t = threadIdx.x;
  const int* src; int n, base; int* out;
  if (bid < 8)       { int h = bid;     src = hq + h*NSEQ + 4096;          n = 4096; base = 4096;          out = q100 + h*4096; }
  else if (bid < 16) { int h = bid - 8; src = hk + h*NSEQ;                 n = 4096; base = 0;             out = k100 + h*4096; }
  else if (bid < 32) { int id = bid-16; int h = id>>1, p = id&1;
                       src = hq + h*NSEQ + p*4096 + 2048;                  n = 2048; base = p*4096 + 2048; out = q101 + id*2048; }
  else               { int id = bid-32; int h = id>>1, p = id&1;
                       src = hk + h*NSEQ + p*4096;                         n = 2048; base = p*4096;       out = k101 + id*2048; }
  const int chunk = n >> 6;
  for (int b = 0; b < 128; ++b) hist[t][b] = 0;
  __syncthreads();
  const int* mysrc = src + t * chunk;
  for (int i = 0; i < chunk; ++i) hist[t][mysrc[i]]++;
  __syncthreads();
  for (int bb = t; bb < 128; bb += 64){
    int s = 0;
    for (int tt = 0; tt < 64; ++tt) s += hist[tt][bb];
    bstart[bb] = s;
  }
  __syncthreads();
  if (t == 0){
    int run = 0;
    for (int b = 0; b < 128; ++b){ int c = bstart[b]; bstart[b] = run; run += c; }
  }
  __syncthreads();
  for (int bb = t; bb < 128; bb += 64){
    unsigned int run = bstart[bb];
    for (int tt = 0; tt < 64; ++tt){ off[tt][bb] = run; run += hist[tt][bb]; }
  }
  __syncthreads();
  for (int i = 0; i < chunk; ++i){
    int hsh = mysrc[i];
    unsigned int pos = off[t][hsh]++;
    out[pos] = base + t * chunk + i;
  }
}

// ================= shared MFMA flash helpers =================
__device__ __forceinline__ void qk_mfma(const v8s qf[2], const char* Ks, int lo, int hi, v4f sa[4]){
#pragma unroll
  for (int st = 0; st < 4; ++st){
#pragma unroll
    for (int kc = 0; kc < 2; ++kc){
      v8s bf = *(const v8s*)(Ks + SWZ(st*16 + lo, kc*64 + hi*16));
      sa[st] = MFMA16(qf[kc], bf, sa[st]);
    }
  }
}

__device__ __forceinline__ void sm_pv(v4f sa[4], char* Pw, const char* VTs,
                                      int lo, int hi, float m[4], float l[4], v4f o[4]){
#pragma unroll
  for (int reg = 0; reg < 4; ++reg){
    float s0 = sa[0][reg], s1 = sa[1][reg], s2 = sa[2][reg], s3 = sa[3][reg];
    float tm = fmaxf(fmaxf(s0, s1), fmaxf(s2, s3));
    tm = fmaxf(tm, __shfl_xor(tm, 1));
    tm = fmaxf(tm, __shfl_xor(tm, 2));
    tm = fmaxf(tm, __shfl_xor(tm, 4));
    tm = fmaxf(tm, __shfl_xor(tm, 8));
    float mn = fmaxf(m[reg], tm);
    float corr = __expf(m[reg] - mn);
    m[reg] = mn;
    float p0 = __expf(s0 - mn), p1 = __expf(s1 - mn);
    float p2 = __expf(s2 - mn), p3 = __expf(s3 - mn);
    int qr = hi*4 + reg;
    *(ushort_t*)(Pw + SWZ(qr, lo*2))        = f2bf(p0);
    *(ushort_t*)(Pw + SWZ(qr, (16+lo)*2))   = f2bf(p1);
    *(ushort_t*)(Pw + SWZ(qr, (32+lo)*2))   = f2bf(p2);
    *(ushort_t*)(Pw + SWZ(qr, (48+lo)*2))   = f2bf(p3);
    float ts = (p0 + p1) + (p2 + p3);
    ts += __shfl_xor(ts, 1);
    ts += __shfl_xor(ts, 2);
    ts += __shfl_xor(ts, 4);
    ts += __shfl_xor(ts, 8);
    l[reg] = l[reg] * corr + ts;
#pragma unroll
    for (int dt = 0; dt < 4; ++dt) o[dt][reg] *= corr;
  }
  asm volatile("" ::: "memory");
#pragma unroll
  for (int kc = 0; kc < 2; ++kc){
    v8s pa = *(const v8s*)(Pw + SWZ(lo, kc*64 + hi*16));
#pragma unroll
    for (int dt = 0; dt < 4; ++dt){
      v8s vb = *(const v8s*)(VTs + SWZ(dt*16 + lo, kc*64 + hi*16));
      o[dt] = MFMA16(pa, vb, o[dt]);
    }
  }
}

// ---------------- 4. diagonal causal (fused balanced pair, 4 waves) ----------------
__global__ __launch_bounds__(256) void diag_mfma(
    const ushort_t* __restrict__ qb, const ushort_t* __restrict__ kb, const ushort_t* __restrict__ vb,
    float* __restrict__ out, float* __restrict__ lse)
{
  __shared__ __align__(16) char Ks[8192];
  __shared__ __align__(16) char VTs[8192];
  __shared__ __align__(16) char Ps[4][2048];
  const int bid = blockIdx.x;
  const int xcd = bid & 7, sl = bid >> 3;
  const int inst = xcd*4 + (sl >> 4);     // all 16 pair-blocks of an instance on one XCD
  const int pi = sl & 15;
  const int h = inst >> 2, tblk = inst & 3;
  const size_t hoff = (size_t)h * NSEQ * D;
  const ushort_t* qh = qb + hoff; const ushort_t* kh = kb + hoff; const ushort_t* vh = vb + hoff;
  const int blkbase = tblk * 2048;
  const int tid = threadIdx.x;
  const int w = tid >> 6, lane = tid & 63;
  const int lo = lane & 15, hi = lane >> 4;
  char* Pw = Ps[w];
  const int srow = tid & 63, spart = tid >> 6;   // K staging: conflict-free
  const int rp = tid & 31, cg = tid >> 5;        // VT staging: 32 banks x 2-way

  const int qt0 = pi, qt1 = 31 - pi;
  v8s qf0[2], qf1[2];
  {
    const ushort_t* r0 = qh + (size_t)(blkbase + qt0*64 + w*16 + lo) * D;
    const ushort_t* r1 = qh + (size_t)(blkbase + qt1*64 + w*16 + lo) * D;
    qf0[0] = *(const v8s*)(r0 + hi*8);  qf0[1] = *(const v8s*)(r0 + 32 + hi*8);
    qf1[0] = *(const v8s*)(r1 + hi*8);  qf1[1] = *(const v8s*)(r1 + 32 + hi*8);
  }
  const v4f vz = {0.0f, 0.0f, 0.0f, 0.0f};
  v4f o0[4], o1[4];
  float m0[4], l0[4], m1[4], l1[4];
#pragma unroll
  for (int i = 0; i < 4; ++i){
    o0[i] = vz; o1[i] = vz;
    m0[i] = -INFINITY; m1[i] = -INFINITY; l0[i] = 0.0f; l1[i] = 0.0f;
  }

#pragma unroll 1
  for (int kt = 0; kt <= qt1; ++kt){
    __syncthreads();
    { // stage K tile (bf16 -> swizzled LDS)
      const ushort_t* srcr = kh + (size_t)(blkbase + kt*64 + srow)*D + spart*16;
      uint4 a = *(const uint4*)srcr;
      uint4 b = *(const uint4*)(srcr + 8);
      *(uint4*)(Ks + SWZ(srow, spart*32)) = a;
      *(uint4*)(Ks + SWZ(srow, spart*32 + 16)) = b;
    }
    { // stage V transposed (packed key-pairs)
      const ushort_t* s0 = vh + (size_t)(blkbase + kt*64 + 2*rp)*D + cg*8;
      uint4 a0 = *(const uint4*)s0;
      uint4 a1 = *(const uint4*)(s0 + D);
      const ushort_t* p0 = (const ushort_t*)&a0;
      const ushort_t* p1 = (const ushort_t*)&a1;
#pragma unroll
      for (int j = 0; j < 8; ++j){
        unsigned int pk = (unsigned int)p0[j] | ((unsigned int)p1[j] << 16);
        *(unsigned int*)(VTs + SWZ(cg*8 + j, rp*4)) = pk;
      }
    }
    __syncthreads();
    { // tile1 (qt1) always
      v4f sa[4] = {vz, vz, vz, vz};
      qk_mfma(qf1, Ks, lo, hi, sa);
#pragma unroll
      for (int st = 0; st < 4; ++st) sa[st] *= SCALE;
      if (kt == qt1){
#pragma unroll
        for (int st = 0; st < 4; ++st){
          int kpl = st*16 + lo;
#pragma unroll
          for (int reg = 0; reg < 4; ++reg)
            if (kpl > w*16 + hi*4 + reg) sa[st][reg] = -INFINITY;
        }
      }
      sm_pv(sa, Pw, VTs, lo, hi, m1, l1, o1);
    }
    if (kt <= qt0){ // tile0 (qt0)
      v4f sa[4] = {vz, vz, vz, vz};
      qk_mfma(qf0, Ks, lo, hi, sa);
#pragma unroll
      for (int st = 0; st < 4; ++st) sa[st] *= SCALE;
      if (kt == qt0){
#pragma unroll
        for (int st = 0; st < 4; ++st){
          int kpl = st*16 + lo;
#pragma unroll
          for (int reg = 0; reg < 4; ++reg)
            if (kpl > w*16 + hi*4 + reg) sa[st][reg] = -INFINITY;
        }
      }
      sm_pv(sa, Pw, VTs, lo, hi, m0, l0, o0);
    }
  }
  // epilogue (both tiles)
#pragma unroll
  for (int reg = 0; reg < 4; ++reg){
    int r1w = blkbase + qt1*64 + w*16 + hi*4 + reg;
    float inv1 = 1.0f / l1[reg];
#pragma unroll
    for (int dt = 0; dt < 4; ++dt)
      out[hoff + (size_t)r1w*D + dt*16 + lo] = o1[dt][reg] * inv1;
    if (lo == 0) lse[h*NSEQ + r1w] = m1[reg] + logf(l1[reg]);
    int r0w = blkbase + qt0*64 + w*16 + hi*4 + reg;
    float inv0 = 1.0f / l0[reg];
#pragma unroll
    for (int dt = 0; dt < 4; ++dt)
      out[hoff + (size_t)r0w*D + dt*16 + lo] = o0[dt][reg] * inv0;
    if (lo == 0) lse[h*NSEQ + r0w] = m0[reg] + logf(l0[reg]);
  }
}

// ---------------- 5/6. LSH no-causal + merge (level 101 / 100), 4 waves ----------------
template<int LEVEL>
__global__ __launch_bounds__(256) void nc_mfma(
    const ushort_t* __restrict__ qb, const ushort_t* __restrict__ kb, const ushort_t* __restrict__ vb,
    float* __restrict__ out, float* __restrict__ lse,
    const int* __restrict__ qidx, const int* __restrict__ kidx, const int* __restrict__ samp)
{
  __shared__ __align__(16) char Ks[8192];
  __shared__ __align__(16) char VTs[8192];
  __shared__ __align__(16) char Ps[4][2048];
  __shared__ int kmk[64];
  const int bid = blockIdx.x;
  int inst, jb;
  if (LEVEL == 101){ int xcd = bid & 7, sl = bid >> 3; inst = xcd*2 + (sl >> 5); jb = sl & 31; }
  else             { inst = bid & 7; jb = bid >> 3; }
  const float delta = (LEVEL == 101) ? 2.0794415416798357f : 2.772588722239781f;
  const int seglen = (LEVEL == 101) ? 2048 : 4096;
  const int* qi = qidx + inst*seglen;
  const int* ki = kidx + inst*seglen;
  const int* sp = samp + inst*256;
  const int h = (LEVEL == 101) ? (inst >> 1) : inst;
  const int qblk = jb >> 2;
  const size_t hoff = (size_t)h * NSEQ * D;
  const ushort_t* qh = qb + hoff; const ushort_t* kh = kb + hoff; const ushort_t* vh = vb + hoff;
  const int tid = threadIdx.x;
  const int w = tid >> 6, lane = tid & 63;
  const int lo = lane & 15, hi = lane >> 4;
  char* Pw = Ps[w];
  const int srow = tid & 63, spart = tid >> 6;
  const int rp = tid & 31, cg = tid >> 5;

  int orig[4];
  v8s qf[2];
  {
    int qrl = qi[jb*64 + w*16 + lo];
    const ushort_t* r = qh + (size_t)qrl * D;
    qf[0] = *(const v8s*)(r + hi*8);
    qf[1] = *(const v8s*)(r + 32 + hi*8);
#pragma unroll
    for (int reg = 0; reg < 4; ++reg) orig[reg] = qi[jb*64 + w*16 + hi*4 + reg];
  }
  const v4f vz = {0.0f, 0.0f, 0.0f, 0.0f};
  v4f o[4]; float m[4], l[4];
#pragma unroll
  for (int i = 0; i < 4; ++i){ o[i] = vz; m[i] = -INFINITY; l[i] = 0.0f; }

#pragma unroll 1
  for (int kt = 0; kt < 8; ++kt){
    __syncthreads();
    { // stage K (gathered)
      int krow, msk = 0;
      if (kt < 4) krow = ki[qblk*256 + kt*64 + srow];
      else { int sidx = sp[(kt-4)*64 + srow]; krow = ki[sidx]; msk = ((sidx >> 8) == qblk) ? 1 : 0; }
      if (spart == 0) kmk[srow] = msk;
      const ushort_t* srcr = kh + (size_t)krow*D + spart*16;
      uint4 a = *(const uint4*)srcr;
      uint4 b = *(const uint4*)(srcr + 8);
      *(uint4*)(Ks + SWZ(srow, spart*32)) = a;
      *(uint4*)(Ks + SWZ(srow, spart*32 + 16)) = b;
    }
    { // stage VT (gathered)
      int r0 = 2*rp, r1 = r0 + 1, g0, g1;
      if (kt < 4){ g0 = ki[qblk*256 + kt*64 + r0]; g1 = ki[qblk*256 + kt*64 + r1]; }
      else       { g0 = ki[sp[(kt-4)*64 + r0]];    g1 = ki[sp[(kt-4)*64 + r1]]; }
      uint4 a0 = *(const uint4*)(vh + (size_t)g0*D + cg*8);
      uint4 a1 = *(const uint4*)(vh + (size_t)g1*D + cg*8);
      const ushort_t* p0 = (const ushort_t*)&a0;
      const ushort_t* p1 = (const ushort_t*)&a1;
#pragma unroll
      for (int j = 0; j < 8; ++j){
        unsigned int pk = (unsigned int)p0[j] | ((unsigned int)p1[j] << 16);
        *(unsigned int*)(VTs + SWZ(cg*8 + j, rp*4)) = pk;
      }
    }
    __syncthreads();
    v4f sa[4] = {vz, vz, vz, vz};
    qk_mfma(qf, Ks, lo, hi, sa);
    if (kt < 4){
#pragma unroll
      for (int st = 0; st < 4; ++st) sa[st] *= SCALE;
    } else {
      int km[4] = { kmk[lo], kmk[16+lo], kmk[32+lo], kmk[48+lo] };
#pragma unroll
      for (int st = 0; st < 4; ++st){
        if (km[st]) sa[st] = (v4f){-INFINITY, -INFINITY, -INFINITY, -INFINITY};
        else        sa[st] = sa[st]*SCALE + delta;
      }
    }
    sm_pv(sa, Pw, VTs, lo, hi, m, l, o);
  }
  // merge epilogue (_add_attn)
#pragma unroll
  for (int reg = 0; reg < 4; ++reg){
    int og = orig[reg];
    float l1v = lse[h*NSEQ + og];
    float l2v = m[reg] + logf(l[reg]);
    float c = 1.0f / (1.0f + __expf(l2v - l1v));
    float inv = (1.0f - c) / l[reg];
#pragma unroll
    for (int dt = 0; dt < 4; ++dt){
      float* ap = out + hoff + (size_t)og*D + dt*16 + lo;
      *ap = c * (*ap) + inv * o[dt][reg];
    }
    if (lo == 0) lse[h*NSEQ + og] = l1v - logf(c + EPSF);
  }
}

// ---------------- launch ----------------
extern "C" void kernel_launch(void* const* d_in, const int* in_sizes, int n_in,
                              void* d_out, int out_size, void* d_ws, size_t ws_size,
                              hipStream_t stream)
{
  const float* q    = (const float*)d_in[0];
  const float* k    = (const float*)d_in[1];
  const float* v    = (const float*)d_in[2];
  const float* proj = (const float*)d_in[3];
  float* out = (float*)d_out;

  char* ws = (char*)d_ws;
  float* lse = (float*)ws;                       // 256 KB
  int* hq   = (int*)(ws + 262144);               // 256 KB
  int* hk   = (int*)(ws + 524288);               // 256 KB
  int* q100 = (int*)(ws + 786432);               // 128 KB
  int* k100 = (int*)(ws + 917504);               // 128 KB
  int* q101 = (int*)(ws + 1048576);              // 128 KB
  int* k101 = (int*)(ws + 1179648);              // 128 KB
  int* s100 = (int*)(ws + 1310720);              // 8 KB
  int* s101 = (int*)(ws + 1318912);              // 16 KB
  ushort_t* qb = (ushort_t*)(ws + 1335296);      // 8 MB each
  ushort_t* kb = qb + (size_t)H*NSEQ*D;
  ushort_t* vb = kb + (size_t)H*NSEQ*D;

  prep_kernel  <<<dim3(6144), dim3(256), 0, stream>>>(q, k, v, qb, kb, vb);
  hash_kernel  <<<dim3(512),  dim3(256), 0, stream>>>(q, k, proj, hq, hk);
  sample_kernel<<<dim3(24),   dim3(256), 0, stream>>>(s100, s101);
  sort_kernel  <<<dim3(48),   dim3(64),  0, stream>>>(hq, hk, q100, k100, q101, k101);
  diag_mfma    <<<dim3(512),  dim3(256), 0, stream>>>(qb, kb, vb, out, lse);
  nc_mfma<101> <<<dim3(512),  dim3(256), 0, stream>>>(qb, kb, vb, out, lse, q101, k101, s101);
  nc_mfma<100> <<<dim3(512),  dim3(256), 0, stream>>>(qb, kb, vb, out, lse, q100, k100, s100);
}